// Round 1
// baseline (454.216 us; speedup 1.0000x reference)
//
#include <hip/hip_runtime.h>
#include <cstddef>
#include <cstdint>

#define NN 4096          // spatial n = 64*64
#define CIN 256          // input channels
#define CQKV 768         // qkv output channels
#define NBATCH 16
#define KSPLIT 4         // column split for context partials
#define QSCALE 0.17677669529663687f  // 32^-0.5

// ---------------------------------------------------------------------------
// Generic per-batch GEMM: Y[b] = A[b] (Mrows x 256) @ B[b] (256 x 4096) (+bias)
// 128x128 tile, BK=8, 256 threads, 8x8 per thread.
// ---------------------------------------------------------------------------
__global__ __launch_bounds__(256)
void gemm_k256(const float* __restrict__ A, size_t a_bstride,
               const float* __restrict__ B, size_t b_bstride,
               float* __restrict__ Y, size_t y_bstride,
               const float* __restrict__ bias)
{
    constexpr int BM = 128, BN = 128, BK = 8;
    const int bz = blockIdx.z;
    const int m0 = blockIdx.y * BM;
    const int n0 = blockIdx.x * BN;
    const float* Ab = A + (size_t)bz * a_bstride;
    const float* Bb = B + (size_t)bz * b_bstride;
    float* Yb = Y + (size_t)bz * y_bstride;

    __shared__ float As[BK][BM + 4];   // stride 132: float4-aligned, conflict-light
    __shared__ float Bs[BK][BN];

    const int t = threadIdx.x;
    const int tx = t & 15;
    const int ty = t >> 4;

    float acc[8][8];
#pragma unroll
    for (int p = 0; p < 8; ++p)
#pragma unroll
        for (int q = 0; q < 8; ++q) acc[p][q] = 0.f;

    for (int k0 = 0; k0 < 256; k0 += BK) {
        {   // A tile: 128 rows x 8 kk, transposed into As[kk][i]
            const int i = t >> 1;
            const int kk4 = (t & 1) * 4;
            const float4 v = *reinterpret_cast<const float4*>(
                &Ab[(size_t)(m0 + i) * 256 + k0 + kk4]);
            As[kk4 + 0][i] = v.x;
            As[kk4 + 1][i] = v.y;
            As[kk4 + 2][i] = v.z;
            As[kk4 + 3][i] = v.w;
        }
        {   // B tile: 8 kk x 128 cols
            const int kk = t >> 5;
            const int j4 = (t & 31) * 4;
            *reinterpret_cast<float4*>(&Bs[kk][j4]) =
                *reinterpret_cast<const float4*>(&Bb[(size_t)(k0 + kk) * NN + n0 + j4]);
        }
        __syncthreads();
#pragma unroll
        for (int kk = 0; kk < BK; ++kk) {
            float a[8], bb[8];
            *reinterpret_cast<float4*>(&a[0]) = *reinterpret_cast<const float4*>(&As[kk][ty * 8]);
            *reinterpret_cast<float4*>(&a[4]) = *reinterpret_cast<const float4*>(&As[kk][ty * 8 + 4]);
            *reinterpret_cast<float4*>(&bb[0]) = *reinterpret_cast<const float4*>(&Bs[kk][tx * 8]);
            *reinterpret_cast<float4*>(&bb[4]) = *reinterpret_cast<const float4*>(&Bs[kk][tx * 8 + 4]);
#pragma unroll
            for (int p = 0; p < 8; ++p)
#pragma unroll
                for (int q = 0; q < 8; ++q)
                    acc[p][q] = fmaf(a[p], bb[q], acc[p][q]);
        }
        __syncthreads();
    }

#pragma unroll
    for (int p = 0; p < 8; ++p) {
        const int row = m0 + ty * 8 + p;
        const float bv = bias ? bias[row] : 0.f;
        float4 v0, v1;
        v0.x = acc[p][0] + bv; v0.y = acc[p][1] + bv; v0.z = acc[p][2] + bv; v0.w = acc[p][3] + bv;
        v1.x = acc[p][4] + bv; v1.y = acc[p][5] + bv; v1.z = acc[p][6] + bv; v1.w = acc[p][7] + bv;
        float* dst = &Yb[(size_t)row * NN + n0 + tx * 8];
        *reinterpret_cast<float4*>(dst) = v0;
        *reinterpret_cast<float4*>(dst + 4) = v1;
    }
}

// ---------------------------------------------------------------------------
// K2: per (b,h,split): partial unnormalized context  C[d][e] = sum_n exp(k[d][n]) v[e][n]
// and partial Z[d] = sum_n exp(k[d][n]).  No max-subtraction needed: k ~ N(0,0.8).
// Each of 4 waves owns a column-phase (c % 4); each lane owns a 4x4 (d,e) tile.
// ---------------------------------------------------------------------------
__global__ __launch_bounds__(256)
void kv_context(const float* __restrict__ qkv,
                float* __restrict__ ctx_part, float* __restrict__ z_part)
{
    const int bh = blockIdx.x;       // b*8 + h
    const int sp = blockIdx.y;       // 0..KSPLIT-1
    const int b = bh >> 3, h = bh & 7;
    const float* kb = qkv + ((size_t)b * CQKV + 256 + h * 32) * NN;
    const float* vb = qkv + ((size_t)b * CQKV + 512 + h * 32) * NN;
    const int c0 = sp * (NN / KSPLIT);

    __shared__ float ek[64][36];     // [col][d]  (stride 36: aligned float4 reads)
    __shared__ float vv[64][36];     // [col][e]

    const int t = threadIdx.x;
    const int lane = t & 63;
    const int w = t >> 6;            // wave id 0..3

    float zloc[8];
#pragma unroll
    for (int p = 0; p < 8; ++p) zloc[p] = 0.f;

    const int d0 = (lane >> 3) * 4;
    const int e0 = (lane & 7) * 4;
    float acc[4][4];
#pragma unroll
    for (int i = 0; i < 4; ++i)
#pragma unroll
        for (int j = 0; j < 4; ++j) acc[i][j] = 0.f;

    for (int cc = 0; cc < NN / KSPLIT; cc += 64) {
#pragma unroll
        for (int p = 0; p < 8; ++p) {
            const int d = w + 4 * p;                       // each wave owns rows {w, w+4, ...}
            const float kvv = kb[(size_t)d * NN + c0 + cc + lane];
            const float e = __expf(kvv);
            zloc[p] += e;
            ek[lane][d] = e;
            vv[lane][d] = vb[(size_t)d * NN + c0 + cc + lane];
        }
        __syncthreads();
#pragma unroll
        for (int ci = 0; ci < 16; ++ci) {
            const int c = w + 4 * ci;                      // wave-uniform column -> broadcast reads
            float ea[4], va[4];
            *reinterpret_cast<float4*>(ea) = *reinterpret_cast<const float4*>(&ek[c][d0]);
            *reinterpret_cast<float4*>(va) = *reinterpret_cast<const float4*>(&vv[c][e0]);
#pragma unroll
            for (int i = 0; i < 4; ++i)
#pragma unroll
                for (int j = 0; j < 4; ++j)
                    acc[i][j] = fmaf(ea[i], va[j], acc[i][j]);
        }
        __syncthreads();
    }

    // write 16 partial groups per (bh,sp): group index = sp*4 + w
    float* dst = ctx_part + (((size_t)bh * KSPLIT + sp) * 4 + w) * 1024 + lane * 16;
#pragma unroll
    for (int i = 0; i < 4; ++i) {
        float4 v;
        v.x = acc[i][0]; v.y = acc[i][1]; v.z = acc[i][2]; v.w = acc[i][3];
        *reinterpret_cast<float4*>(&dst[i * 4]) = v;
    }

    // Z reduction: each row owned by exactly one wave
#pragma unroll
    for (int p = 0; p < 8; ++p) {
        float z = zloc[p];
#pragma unroll
        for (int off = 32; off >= 1; off >>= 1) z += __shfl_xor(z, off);
        if (lane == 0) z_part[((size_t)bh * KSPLIT + sp) * 32 + (w + 4 * p)] = z;
    }
}

// ---------------------------------------------------------------------------
// K3: q softmax over d=32 (axis -2) * SCALE, in place on qkv rows [0,256)
// ---------------------------------------------------------------------------
__global__ __launch_bounds__(256)
void qsoftmax(float* __restrict__ qkv)
{
    const int b = blockIdx.y;
    const int n = blockIdx.x * 256 + threadIdx.x;
    float* qb = qkv + (size_t)b * CQKV * NN;
    for (int h = 0; h < 8; ++h) {
        float vals[32];
        float mx = -1e30f;
#pragma unroll
        for (int d = 0; d < 32; ++d) {
            vals[d] = qb[(size_t)(h * 32 + d) * NN + n];
            mx = fmaxf(mx, vals[d]);
        }
        float s = 0.f;
#pragma unroll
        for (int d = 0; d < 32; ++d) {
            vals[d] = __expf(vals[d] - mx);
            s += vals[d];
        }
        const float inv = QSCALE / s;
#pragma unroll
        for (int d = 0; d < 32; ++d)
            qb[(size_t)(h * 32 + d) * NN + n] = vals[d] * inv;
    }
}

// ---------------------------------------------------------------------------
// K4: reduce context partials, normalize by Z, fold in w_out:
//   M[b][o][h*32+d] = (1/Z[d]) * sum_e w_out[o][h*32+e] * ctx[b][h][d][e]
// ---------------------------------------------------------------------------
__global__ __launch_bounds__(256)
void make_m(const float* __restrict__ ctx_part, const float* __restrict__ z_part,
            const float* __restrict__ w_out, float* __restrict__ Mmat)
{
    const int h = blockIdx.x;
    const int b = blockIdx.y;
    const int bh = b * 8 + h;
    const int t = threadIdx.x;

    __shared__ float ctx[32][33];
    __shared__ float zinv[32];

    for (int lin = t; lin < 1024; lin += 256) {
        const int g = lin >> 4, i = (lin >> 2) & 3, j = lin & 3;
        const int d = ((g >> 3) << 2) + i;
        const int e = ((g & 7) << 2) + j;
        float s = 0.f;
#pragma unroll
        for (int p = 0; p < 16; ++p)
            s += ctx_part[((size_t)bh * 16 + p) * 1024 + lin];
        ctx[d][e] = s;
    }
    if (t < 32) {
        float z = 0.f;
#pragma unroll
        for (int sp = 0; sp < KSPLIT; ++sp)
            z += z_part[((size_t)bh * KSPLIT + sp) * 32 + t];
        zinv[t] = 1.f / z;
    }
    __syncthreads();

    const int o = t;
    float wrow[32];
#pragma unroll
    for (int e = 0; e < 32; ++e)
        wrow[e] = w_out[(size_t)o * 256 + h * 32 + e];
#pragma unroll 4
    for (int d = 0; d < 32; ++d) {
        float s = 0.f;
#pragma unroll
        for (int e = 0; e < 32; ++e)
            s = fmaf(wrow[e], ctx[d][e], s);
        Mmat[((size_t)b * 256 + o) * 256 + h * 32 + d] = s * zinv[d];
    }
}

// ---------------------------------------------------------------------------
extern "C" void kernel_launch(void* const* d_in, const int* in_sizes, int n_in,
                              void* d_out, int out_size, void* d_ws, size_t ws_size,
                              hipStream_t stream)
{
    const float* x     = (const float*)d_in[0];   // (16,256,64,64)
    const float* w_qkv = (const float*)d_in[1];   // (768,256)
    const float* w_out = (const float*)d_in[2];   // (256,256)
    const float* b_out = (const float*)d_in[3];   // (256,)
    float* out = (float*)d_out;                   // (16,256,64,64)

    char* ws = (char*)d_ws;
    float* qkv = (float*)ws;                                       // 16*768*4096 f32 = 192 MiB
    size_t off = (size_t)NBATCH * CQKV * NN * sizeof(float);
    float* ctx_part = (float*)(ws + off);                          // 128*16*1024 f32 = 8 MiB
    off += (size_t)128 * 16 * 1024 * sizeof(float);
    float* z_part = (float*)(ws + off);                            // 128*4*32 f32
    off += (size_t)128 * KSPLIT * 32 * sizeof(float);
    float* Mmat = (float*)(ws + off);                              // 16*256*256 f32 = 4 MiB

    // K1: qkv[b] = w_qkv @ x[b]
    gemm_k256<<<dim3(32, 6, NBATCH), 256, 0, stream>>>(
        w_qkv, 0, x, (size_t)CIN * NN, qkv, (size_t)CQKV * NN, nullptr);

    // K2: context partials (k softmax numerator + Z) per (b,h)
    kv_context<<<dim3(128, KSPLIT), 256, 0, stream>>>(qkv, ctx_part, z_part);

    // K3: q softmax (axis d) * SCALE, in place
    qsoftmax<<<dim3(NN / 256, NBATCH), 256, 0, stream>>>(qkv);

    // K4: M[b] = fold(w_out, normalized context)
    make_m<<<dim3(8, NBATCH), 256, 0, stream>>>(ctx_part, z_part, w_out, Mmat);

    // K5: out[b] = M[b] @ q[b] + b_out
    gemm_k256<<<dim3(32, 2, NBATCH), 256, 0, stream>>>(
        Mmat, 256 * 256, qkv, (size_t)CQKV * NN, out, (size_t)CIN * NN, b_out);
}

// Round 2
// 151.691 us; speedup vs baseline: 2.9943x; 2.9943x over previous
//
#include <hip/hip_runtime.h>
#include <cstddef>
#include <cstdint>

#define NN 4096          // spatial n = 64*64
#define CIN 256          // input channels
#define CQKV 768         // qkv output channels
#define NBATCH 16
#define KSPLIT 4
#define QSCALE 0.17677669529663687f  // 32^-0.5

typedef short s16x8 __attribute__((ext_vector_type(8)));
typedef float f32x4 __attribute__((ext_vector_type(4)));

__device__ __forceinline__ float bf2f(unsigned short u) {
    unsigned int x = ((unsigned int)u) << 16;
    return __builtin_bit_cast(float, x);
}
__device__ __forceinline__ unsigned short f2bf(float f) {
    unsigned int u = __builtin_bit_cast(unsigned int, f);
    return (unsigned short)((u + 0x7fffu + ((u >> 16) & 1u)) >> 16);   // RNE
}
__device__ __forceinline__ void glds16(const void* gsrc, void* lds) {
    __builtin_amdgcn_global_load_lds(
        (const __attribute__((address_space(1))) unsigned int*)gsrc,
        (__attribute__((address_space(3))) unsigned int*)lds,
        16, 0, 0);
}

// ---------------------------------------------------------------------------
// K0a: x [b][256][4096] f32  ->  xT [b][4096][256] bf16   (transpose + cast)
// ---------------------------------------------------------------------------
__global__ __launch_bounds__(256)
void xpose(const float* __restrict__ x, unsigned short* __restrict__ xT)
{
    const int b = blockIdx.z;
    const int n0 = blockIdx.x * 64, c0 = blockIdx.y * 64;
    __shared__ float xs[64][65];
    const int t = threadIdx.x;
    const float* xb = x + (size_t)b * CIN * NN;
#pragma unroll
    for (int p = 0; p < 4; ++p) {
        const int row = p * 16 + (t >> 4);     // c-local
        const int col = (t & 15) * 4;          // n-local
        const float4 v = *reinterpret_cast<const float4*>(
            &xb[(size_t)(c0 + row) * NN + n0 + col]);
        xs[col + 0][row] = v.x; xs[col + 1][row] = v.y;
        xs[col + 2][row] = v.z; xs[col + 3][row] = v.w;
    }
    __syncthreads();
    const int n = t >> 2, cch = (t & 3) * 16;
    unsigned short arr[16];
#pragma unroll
    for (int e = 0; e < 16; ++e) arr[e] = f2bf(xs[n][cch + e]);
    unsigned short* dst = xT + ((size_t)b * NN + n0 + n) * 256 + c0 + cch;
    *reinterpret_cast<s16x8*>(&dst[0]) = *reinterpret_cast<s16x8*>(&arr[0]);
    *reinterpret_cast<s16x8*>(&dst[8]) = *reinterpret_cast<s16x8*>(&arr[8]);
}

// K0b: w_qkv f32 -> bf16 (tiny)
__global__ __launch_bounds__(256)
void wcvt(const float* __restrict__ w, unsigned short* __restrict__ wb)
{
    const int i = (blockIdx.x * 256 + threadIdx.x) * 4;
    const float4 v = *reinterpret_cast<const float4*>(&w[i]);
    unsigned short a[4] = { f2bf(v.x), f2bf(v.y), f2bf(v.z), f2bf(v.w) };
    *reinterpret_cast<ushort2*>(&wb[i])     = *reinterpret_cast<ushort2*>(&a[0]);
    *reinterpret_cast<ushort2*>(&wb[i + 2]) = *reinterpret_cast<ushort2*>(&a[2]);
}

// ---------------------------------------------------------------------------
// MFMA GEMM (m97 structure): Y[b] = A[b] (M x 256) @ B[b] (256 x 4096)
// A row-major [M][256] bf16, BT row-major [4096][256] bf16 (i.e. B transposed).
// 128x128 tile, BK=32, 4 waves (2x2 of 64x64), 16x16x32 bf16 MFMA.
// ---------------------------------------------------------------------------
template<int BF16OUT>
__global__ __launch_bounds__(256)
void gemm_mfma(const unsigned short* __restrict__ A, size_t a_bstride,
               const unsigned short* __restrict__ BT, size_t bt_bstride,
               void* __restrict__ Y, size_t y_bstride,
               const float* __restrict__ bias)
{
    __shared__ unsigned short Asm[128 * 32];   // [row][k] 64 B rows
    __shared__ unsigned short Bsm[128 * 32];
    const int t = threadIdx.x;
    const int bz = blockIdx.z;
    const int m0 = blockIdx.y * 128, n0 = blockIdx.x * 128;
    const unsigned short* Ab = A + (size_t)bz * a_bstride;
    const unsigned short* Bb = BT + (size_t)bz * bt_bstride;

    const int lane = t & 63;
    const int lr = lane & 15, lq = lane >> 4;
    const int w = t >> 6;
    const int wr = (w >> 1) * 64, wc = (w & 1) * 64;

    const int srow = t >> 2;           // staging row 0..63 (+64 for 2nd issue)
    const int scol = (t & 3) * 8;      // k-elems within 32-wide slice
    char* AsmB = (char*)Asm + (w << 10);   // wave-uniform LDS base
    char* BsmB = (char*)Bsm + (w << 10);

    f32x4 acc[4][4] = {};

    for (int k0 = 0; k0 < 256; k0 += 32) {
        glds16(Ab + (size_t)(m0 + srow) * 256 + k0 + scol,      AsmB);
        glds16(Ab + (size_t)(m0 + srow + 64) * 256 + k0 + scol, AsmB + 4096);
        glds16(Bb + (size_t)(n0 + srow) * 256 + k0 + scol,      BsmB);
        glds16(Bb + (size_t)(n0 + srow + 64) * 256 + k0 + scol, BsmB + 4096);
        __syncthreads();

        s16x8 af[4], bf[4];
#pragma unroll
        for (int m = 0; m < 4; ++m)
            af[m] = *reinterpret_cast<const s16x8*>(&Asm[(wr + m * 16 + lr) * 32 + lq * 8]);
#pragma unroll
        for (int n = 0; n < 4; ++n)
            bf[n] = *reinterpret_cast<const s16x8*>(&Bsm[(wc + n * 16 + lr) * 32 + lq * 8]);
#pragma unroll
        for (int m = 0; m < 4; ++m)
#pragma unroll
            for (int n = 0; n < 4; ++n)
                acc[m][n] = __builtin_amdgcn_mfma_f32_16x16x32_bf16(af[m], bf[n], acc[m][n], 0, 0, 0);
        __syncthreads();
    }

    // C/D mapping: col = lane&15, row = (lane>>4)*4 + reg
    if (BF16OUT) {
        unsigned short* Yb = (unsigned short*)Y + (size_t)bz * y_bstride;
#pragma unroll
        for (int m = 0; m < 4; ++m)
#pragma unroll
            for (int r = 0; r < 4; ++r) {
                const int row = m0 + wr + m * 16 + lq * 4 + r;
#pragma unroll
                for (int n = 0; n < 4; ++n)
                    Yb[(size_t)row * NN + n0 + wc + n * 16 + lr] = f2bf(acc[m][n][r]);
            }
    } else {
        float* Yb = (float*)Y + (size_t)bz * y_bstride;
#pragma unroll
        for (int m = 0; m < 4; ++m)
#pragma unroll
            for (int r = 0; r < 4; ++r) {
                const int row = m0 + wr + m * 16 + lq * 4 + r;
                const float bv = bias ? bias[row] : 0.f;
#pragma unroll
                for (int n = 0; n < 4; ++n)
                    Yb[(size_t)row * NN + n0 + wc + n * 16 + lr] = acc[m][n][r] + bv;
            }
    }
}

// ---------------------------------------------------------------------------
// K2: partial unnormalized context C[d][e] = sum_n exp(k[d][n]) v[e][n], plus
// partial Z[d]. k,v read as bf16. No max-subtraction (k ~ N(0,0.8)).
// ---------------------------------------------------------------------------
__global__ __launch_bounds__(256)
void kv_context(const unsigned short* __restrict__ qkv,
                float* __restrict__ ctx_part, float* __restrict__ z_part)
{
    const int bh = blockIdx.x;
    const int sp = blockIdx.y;
    const int b = bh >> 3, h = bh & 7;
    const unsigned short* kb = qkv + ((size_t)b * CQKV + 256 + h * 32) * NN;
    const unsigned short* vb = qkv + ((size_t)b * CQKV + 512 + h * 32) * NN;
    const int c0 = sp * (NN / KSPLIT);

    __shared__ float ek[64][36];
    __shared__ float vv[64][36];

    const int t = threadIdx.x;
    const int lane = t & 63;
    const int w = t >> 6;

    float zloc[8];
#pragma unroll
    for (int p = 0; p < 8; ++p) zloc[p] = 0.f;

    const int d0 = (lane >> 3) * 4;
    const int e0 = (lane & 7) * 4;
    float acc[4][4];
#pragma unroll
    for (int i = 0; i < 4; ++i)
#pragma unroll
        for (int j = 0; j < 4; ++j) acc[i][j] = 0.f;

    for (int cc = 0; cc < NN / KSPLIT; cc += 64) {
#pragma unroll
        for (int p = 0; p < 8; ++p) {
            const int d = w + 4 * p;
            const float kvv = bf2f(kb[(size_t)d * NN + c0 + cc + lane]);
            const float e = __expf(kvv);
            zloc[p] += e;
            ek[lane][d] = e;
            vv[lane][d] = bf2f(vb[(size_t)d * NN + c0 + cc + lane]);
        }
        __syncthreads();
#pragma unroll
        for (int ci = 0; ci < 16; ++ci) {
            const int c = w + 4 * ci;
            float ea[4], va[4];
            *reinterpret_cast<float4*>(ea) = *reinterpret_cast<const float4*>(&ek[c][d0]);
            *reinterpret_cast<float4*>(va) = *reinterpret_cast<const float4*>(&vv[c][e0]);
#pragma unroll
            for (int i = 0; i < 4; ++i)
#pragma unroll
                for (int j = 0; j < 4; ++j)
                    acc[i][j] = fmaf(ea[i], va[j], acc[i][j]);
        }
        __syncthreads();
    }

    float* dst = ctx_part + (((size_t)bh * KSPLIT + sp) * 4 + w) * 1024 + lane * 16;
#pragma unroll
    for (int i = 0; i < 4; ++i) {
        float4 v;
        v.x = acc[i][0]; v.y = acc[i][1]; v.z = acc[i][2]; v.w = acc[i][3];
        *reinterpret_cast<float4*>(&dst[i * 4]) = v;
    }
#pragma unroll
    for (int p = 0; p < 8; ++p) {
        float z = zloc[p];
#pragma unroll
        for (int off = 32; off >= 1; off >>= 1) z += __shfl_xor(z, off);
        if (lane == 0) z_part[((size_t)bh * KSPLIT + sp) * 32 + (w + 4 * p)] = z;
    }
}

// ---------------------------------------------------------------------------
// K3: q softmax over d (per head) * SCALE, bf16 in, writes qT [b][n][256] bf16
// ---------------------------------------------------------------------------
__global__ __launch_bounds__(256)
void qsm_t(const unsigned short* __restrict__ qkv, unsigned short* __restrict__ qT)
{
    const int b = blockIdx.y;
    const int n = blockIdx.x * 256 + threadIdx.x;
    const unsigned short* qb = qkv + (size_t)b * CQKV * NN;
    unsigned short* qtb = qT + ((size_t)b * NN + n) * 256;
    for (int h = 0; h < 8; ++h) {
        float vals[32];
        float mx = -1e30f;
#pragma unroll
        for (int d = 0; d < 32; ++d) {
            vals[d] = bf2f(qb[(size_t)(h * 32 + d) * NN + n]);
            mx = fmaxf(mx, vals[d]);
        }
        float s = 0.f;
#pragma unroll
        for (int d = 0; d < 32; ++d) {
            vals[d] = __expf(vals[d] - mx);
            s += vals[d];
        }
        const float inv = QSCALE / s;
        unsigned short arr[32];
#pragma unroll
        for (int d = 0; d < 32; ++d) arr[d] = f2bf(vals[d] * inv);
#pragma unroll
        for (int i = 0; i < 4; ++i)
            *reinterpret_cast<s16x8*>(&qtb[h * 32 + i * 8]) =
                *reinterpret_cast<s16x8*>(&arr[i * 8]);
    }
}

// ---------------------------------------------------------------------------
// K4: reduce context partials, normalize by Z, fold in w_out -> Mmat bf16
// ---------------------------------------------------------------------------
__global__ __launch_bounds__(256)
void make_m(const float* __restrict__ ctx_part, const float* __restrict__ z_part,
            const float* __restrict__ w_out, unsigned short* __restrict__ Mmat)
{
    const int h = blockIdx.x;
    const int b = blockIdx.y;
    const int bh = b * 8 + h;
    const int t = threadIdx.x;

    __shared__ float ctx[32][33];
    __shared__ float zinv[32];

    for (int lin = t; lin < 1024; lin += 256) {
        const int g = lin >> 4, i = (lin >> 2) & 3, j = lin & 3;
        const int d = ((g >> 3) << 2) + i;
        const int e = ((g & 7) << 2) + j;
        float s = 0.f;
#pragma unroll
        for (int p = 0; p < 16; ++p)
            s += ctx_part[((size_t)bh * 16 + p) * 1024 + lin];
        ctx[d][e] = s;
    }
    if (t < 32) {
        float z = 0.f;
#pragma unroll
        for (int sp = 0; sp < KSPLIT; ++sp)
            z += z_part[((size_t)bh * KSPLIT + sp) * 32 + t];
        zinv[t] = 1.f / z;
    }
    __syncthreads();

    const int o = t;
    float wrow[32];
#pragma unroll
    for (int e = 0; e < 32; ++e)
        wrow[e] = w_out[(size_t)o * 256 + h * 32 + e];
#pragma unroll 4
    for (int d = 0; d < 32; ++d) {
        float s = 0.f;
#pragma unroll
        for (int e = 0; e < 32; ++e)
            s = fmaf(wrow[e], ctx[d][e], s);
        Mmat[((size_t)b * 256 + o) * 256 + h * 32 + d] = f2bf(s * zinv[d]);
    }
}

// ---------------------------------------------------------------------------
extern "C" void kernel_launch(void* const* d_in, const int* in_sizes, int n_in,
                              void* d_out, int out_size, void* d_ws, size_t ws_size,
                              hipStream_t stream)
{
    const float* x     = (const float*)d_in[0];
    const float* w_qkv = (const float*)d_in[1];
    const float* w_out = (const float*)d_in[2];
    const float* b_out = (const float*)d_in[3];
    float* out = (float*)d_out;

    char* ws = (char*)d_ws;
    size_t off = 0;
    unsigned short* qkv = (unsigned short*)(ws + off);  off += (size_t)NBATCH * CQKV * NN * 2;   // 96 MiB
    unsigned short* xT  = (unsigned short*)(ws + off);  off += (size_t)NBATCH * NN * CIN * 2;    // 32 MiB
    unsigned short* qT  = (unsigned short*)(ws + off);  off += (size_t)NBATCH * NN * CIN * 2;    // 32 MiB
    float* ctx_part     = (float*)(ws + off);           off += (size_t)128 * 16 * 1024 * 4;      // 8 MiB
    float* z_part       = (float*)(ws + off);           off += (size_t)128 * KSPLIT * 32 * 4;
    unsigned short* Mmat= (unsigned short*)(ws + off);  off += (size_t)NBATCH * 256 * 256 * 2;   // 2 MiB
    unsigned short* wb  = (unsigned short*)(ws + off);  off += (size_t)CQKV * CIN * 2;

    // K0: transpose+cast x, cast w_qkv
    xpose<<<dim3(NN / 64, CIN / 64, NBATCH), 256, 0, stream>>>(x, xT);
    wcvt<<<dim3(CQKV * CIN / 1024), 256, 0, stream>>>(w_qkv, wb);

    // K1: qkv[b] = w_qkv @ x[b]   (bf16 MFMA, bf16 out)
    gemm_mfma<1><<<dim3(32, 6, NBATCH), 256, 0, stream>>>(
        wb, 0, xT, (size_t)NN * CIN, qkv, (size_t)CQKV * NN, nullptr);

    // K2: context partials
    kv_context<<<dim3(128, KSPLIT), 256, 0, stream>>>(qkv, ctx_part, z_part);

    // K3: q softmax + transpose -> qT bf16
    qsm_t<<<dim3(NN / 256, NBATCH), 256, 0, stream>>>(qkv, qT);

    // K4: Mmat[b] = fold(w_out, normalized context)  (bf16 out)
    make_m<<<dim3(8, NBATCH), 256, 0, stream>>>(ctx_part, z_part, w_out, Mmat);

    // K5: out[b] = Mmat[b] @ q[b] + b_out   (bf16 MFMA, f32 out)
    gemm_mfma<0><<<dim3(32, 2, NBATCH), 256, 0, stream>>>(
        Mmat, (size_t)256 * 256, qT, (size_t)NN * CIN, out, (size_t)CIN * NN, b_out);
}

// Round 3
// 126.036 us; speedup vs baseline: 3.6039x; 1.2036x over previous
//
#include <hip/hip_runtime.h>
#include <cstddef>
#include <cstdint>

#define NN 4096          // spatial n = 64*64
#define CIN 256          // input channels
#define CQKV 768         // qkv output channels
#define NBATCH 16
#define KSPLIT 4
#define QSCALE 0.17677669529663687f  // 32^-0.5

typedef short s16x8 __attribute__((ext_vector_type(8)));
typedef float f32x4 __attribute__((ext_vector_type(4)));

__device__ __forceinline__ float bf2f(unsigned short u) {
    unsigned int x = ((unsigned int)u) << 16;
    return __builtin_bit_cast(float, x);
}
__device__ __forceinline__ unsigned short f2bf(float f) {
    unsigned int u = __builtin_bit_cast(unsigned int, f);
    return (unsigned short)((u + 0x7fffu + ((u >> 16) & 1u)) >> 16);   // RNE
}
__device__ __forceinline__ void glds16(const void* gsrc, void* lds) {
    __builtin_amdgcn_global_load_lds(
        (const __attribute__((address_space(1))) unsigned int*)gsrc,
        (__attribute__((address_space(3))) unsigned int*)lds,
        16, 0, 0);
}

// ---------------------------------------------------------------------------
// Shared GEMM core: acc(128x128) = A[m0:+128][0:256] @ BT[n0:+128][0:256]^T
// BK=64, double-buffered LDS (4 x 16KB), XOR-swizzled chunks (rule #21:
// linear LDS dest for global_load_lds + pre-swizzled global source + same
// XOR on the ds_read side). 4 waves, 2x2 of 64x64, mfma 16x16x32 bf16.
// ---------------------------------------------------------------------------
__device__ __forceinline__ void gemm_core(const unsigned short* __restrict__ Ab,
                                          const unsigned short* __restrict__ Bb,
                                          int m0, int n0, char* smem,
                                          f32x4 (&acc)[4][4])
{
    const int t = threadIdx.x;
    const int lane = t & 63, w = t >> 6;
    const int lr = lane & 15, lq = lane >> 4;
    const int wr = (w >> 1) * 64, wc = (w & 1) * 64;
    const int srow = t >> 3;                    // 0..31: row within 32-row issue
    const int schunk = (t & 7) ^ (srow & 7);    // pre-swizzled 16B chunk
    const int wq = w << 10;                     // wave-uniform LDS sub-base
    const int xr = lr & 7;                      // read-side XOR

    char* A0 = smem;          char* B0 = smem + 16384;
    char* A1 = smem + 32768;  char* B1 = smem + 49152;

#define STG(bufA, bufB, k0)                                                     \
    { _Pragma("unroll") for (int i = 0; i < 4; ++i)                             \
        glds16(Ab + (size_t)(m0 + i*32 + srow)*256 + (k0) + schunk*8,           \
               (bufA) + i*4096 + wq);                                           \
      _Pragma("unroll") for (int i = 0; i < 4; ++i)                             \
        glds16(Bb + (size_t)(n0 + i*32 + srow)*256 + (k0) + schunk*8,           \
               (bufB) + i*4096 + wq); }

#define CMP(bufA, bufB)                                                         \
    { s16x8 af[4][2], bfr[4][2];                                                \
      _Pragma("unroll") for (int m = 0; m < 4; ++m) {                           \
        const char* rp = (bufA) + (wr + m*16 + lr)*128;                         \
        af[m][0] = *(const s16x8*)(rp + (((0*4 + lq) ^ xr) << 4));              \
        af[m][1] = *(const s16x8*)(rp + (((1*4 + lq) ^ xr) << 4)); }            \
      _Pragma("unroll") for (int n = 0; n < 4; ++n) {                           \
        const char* rp = (bufB) + (wc + n*16 + lr)*128;                         \
        bfr[n][0] = *(const s16x8*)(rp + (((0*4 + lq) ^ xr) << 4));             \
        bfr[n][1] = *(const s16x8*)(rp + (((1*4 + lq) ^ xr) << 4)); }           \
      _Pragma("unroll") for (int m = 0; m < 4; ++m)                             \
      _Pragma("unroll") for (int n = 0; n < 4; ++n) {                           \
        acc[m][n] = __builtin_amdgcn_mfma_f32_16x16x32_bf16(af[m][0], bfr[n][0], acc[m][n], 0, 0, 0); \
        acc[m][n] = __builtin_amdgcn_mfma_f32_16x16x32_bf16(af[m][1], bfr[n][1], acc[m][n], 0, 0, 0); }}

    STG(A0, B0, 0);
    __syncthreads();            // drains vmcnt(0): buf0 staged
    STG(A1, B1, 64);            // prefetch flies under CMP(A0,B0)
    CMP(A0, B0);
    __syncthreads();
    STG(A0, B0, 128);
    CMP(A1, B1);
    __syncthreads();
    STG(A1, B1, 192);
    CMP(A0, B0);
    __syncthreads();
    CMP(A1, B1);
#undef STG
#undef CMP
}

// ---------------------------------------------------------------------------
// K1: qkv = w_qkv @ x  per batch.  q-rows (m0<256): fused softmax-over-d
// (+SCALE) and transpose -> qT [b][n][256] bf16.  k/v rows: bf16 into qkv.
// ---------------------------------------------------------------------------
__global__ __launch_bounds__(256, 2)
void gemm_qkv(const unsigned short* __restrict__ wb,
              const unsigned short* __restrict__ xT,
              unsigned short* __restrict__ qkv,
              unsigned short* __restrict__ qT)
{
    __shared__ __align__(16) char smem[65536];
    const int bz = blockIdx.z;
    const int m0 = blockIdx.y * 128, n0 = blockIdx.x * 128;
    const unsigned short* Bb = xT + (size_t)bz * NN * 256;

    f32x4 acc[4][4] = {};
    gemm_core(wb, Bb, m0, n0, smem, acc);

    const int t = threadIdx.x;
    const int lane = t & 63, w = t >> 6;
    const int lr = lane & 15, lq = lane >> 4;
    const int wr = (w >> 1) * 64, wc = (w & 1) * 64;

    if (m0 < 256) {
        // ---- q path: softmax over d=32 (per head, per column) ----
        __syncthreads();   // all waves done reading stage LDS before reuse
        unsigned short (*qs)[136] = (unsigned short (*)[136])smem;  // [n_loc][c_loc]
#pragma unroll
        for (int n = 0; n < 4; ++n) {
            const int col = wc + n * 16 + lr;
#pragma unroll
            for (int hp = 0; hp < 2; ++hp) {
                float mx = -1e30f;
#pragma unroll
                for (int u = 0; u < 2; ++u)
#pragma unroll
                    for (int r = 0; r < 4; ++r)
                        mx = fmaxf(mx, acc[hp * 2 + u][n][r]);
                mx = fmaxf(mx, __shfl_xor(mx, 16));
                mx = fmaxf(mx, __shfl_xor(mx, 32));
                float er[2][4];
                float s = 0.f;
#pragma unroll
                for (int u = 0; u < 2; ++u)
#pragma unroll
                    for (int r = 0; r < 4; ++r) {
                        er[u][r] = __expf(acc[hp * 2 + u][n][r] - mx);
                        s += er[u][r];
                    }
                s += __shfl_xor(s, 16);
                s += __shfl_xor(s, 32);
                const float inv = QSCALE / s;
#pragma unroll
                for (int u = 0; u < 2; ++u) {
                    ushort4 pk;
                    pk.x = f2bf(er[u][0] * inv);
                    pk.y = f2bf(er[u][1] * inv);
                    pk.z = f2bf(er[u][2] * inv);
                    pk.w = f2bf(er[u][3] * inv);
                    *(ushort4*)&qs[col][wr + (hp * 2 + u) * 16 + lq * 4] = pk;
                }
            }
        }
        __syncthreads();
        // copy out: qT[b][n0+nl][m0 + 0..128)
        const int nl = t >> 1, half = t & 1;
        const unsigned short* src = &qs[nl][half * 64];
        unsigned short* dst = qT + ((size_t)bz * NN + n0 + nl) * 256 + m0 + half * 64;
#pragma unroll
        for (int i = 0; i < 8; ++i)
            *(s16x8*)(dst + i * 8) = *(const s16x8*)(src + i * 8);
    } else {
        // ---- k/v path: plain bf16 store into qkv ----
        unsigned short* Yb = qkv + (size_t)bz * CQKV * NN;
#pragma unroll
        for (int m = 0; m < 4; ++m)
#pragma unroll
            for (int r = 0; r < 4; ++r) {
                const int row = m0 + wr + m * 16 + lq * 4 + r;
#pragma unroll
                for (int n = 0; n < 4; ++n)
                    Yb[(size_t)row * NN + n0 + wc + n * 16 + lr] = f2bf(acc[m][n][r]);
            }
    }
}

// ---------------------------------------------------------------------------
// K5: out = Mmat @ q + bias  (f32 out)
// ---------------------------------------------------------------------------
__global__ __launch_bounds__(256, 2)
void gemm_out(const unsigned short* __restrict__ Mmat,
              const unsigned short* __restrict__ qT,
              float* __restrict__ out, const float* __restrict__ bias)
{
    __shared__ __align__(16) char smem[65536];
    const int bz = blockIdx.z;
    const int m0 = blockIdx.y * 128, n0 = blockIdx.x * 128;
    const unsigned short* Ab = Mmat + (size_t)bz * 256 * 256;
    const unsigned short* Bb = qT + (size_t)bz * NN * 256;

    f32x4 acc[4][4] = {};
    gemm_core(Ab, Bb, m0, n0, smem, acc);

    const int t = threadIdx.x;
    const int lane = t & 63, w = t >> 6;
    const int lr = lane & 15, lq = lane >> 4;
    const int wr = (w >> 1) * 64, wc = (w & 1) * 64;

    float* Yb = out + (size_t)bz * CIN * NN;
#pragma unroll
    for (int m = 0; m < 4; ++m)
#pragma unroll
        for (int r = 0; r < 4; ++r) {
            const int row = m0 + wr + m * 16 + lq * 4 + r;
            const float bv = bias[row];
#pragma unroll
            for (int n = 0; n < 4; ++n)
                Yb[(size_t)row * NN + n0 + wc + n * 16 + lr] = acc[m][n][r] + bv;
        }
}

// ---------------------------------------------------------------------------
// K0a: x [b][256][4096] f32  ->  xT [b][4096][256] bf16   (transpose + cast)
// ---------------------------------------------------------------------------
__global__ __launch_bounds__(256)
void xpose(const float* __restrict__ x, unsigned short* __restrict__ xT)
{
    const int b = blockIdx.z;
    const int n0 = blockIdx.x * 64, c0 = blockIdx.y * 64;
    __shared__ float xs[64][65];
    const int t = threadIdx.x;
    const float* xb = x + (size_t)b * CIN * NN;
#pragma unroll
    for (int p = 0; p < 4; ++p) {
        const int row = p * 16 + (t >> 4);
        const int col = (t & 15) * 4;
        const float4 v = *reinterpret_cast<const float4*>(
            &xb[(size_t)(c0 + row) * NN + n0 + col]);
        xs[col + 0][row] = v.x; xs[col + 1][row] = v.y;
        xs[col + 2][row] = v.z; xs[col + 3][row] = v.w;
    }
    __syncthreads();
    const int n = t >> 2, cch = (t & 3) * 16;
    unsigned short arr[16];
#pragma unroll
    for (int e = 0; e < 16; ++e) arr[e] = f2bf(xs[n][cch + e]);
    unsigned short* dst = xT + ((size_t)b * NN + n0 + n) * 256 + c0 + cch;
    *reinterpret_cast<s16x8*>(&dst[0]) = *reinterpret_cast<s16x8*>(&arr[0]);
    *reinterpret_cast<s16x8*>(&dst[8]) = *reinterpret_cast<s16x8*>(&arr[8]);
}

// K0b: w_qkv f32 -> bf16
__global__ __launch_bounds__(256)
void wcvt(const float* __restrict__ w, unsigned short* __restrict__ wb)
{
    const int i = (blockIdx.x * 256 + threadIdx.x) * 4;
    const float4 v = *reinterpret_cast<const float4*>(&w[i]);
    unsigned short a[4] = { f2bf(v.x), f2bf(v.y), f2bf(v.z), f2bf(v.w) };
    *reinterpret_cast<ushort2*>(&wb[i])     = *reinterpret_cast<ushort2*>(&a[0]);
    *reinterpret_cast<ushort2*>(&wb[i + 2]) = *reinterpret_cast<ushort2*>(&a[2]);
}

// ---------------------------------------------------------------------------
// K2: partial unnormalized context C[d][e] = sum_n exp(k[d][n]) v[e][n], plus
// partial Z[d]. k,v read as bf16. No max-subtraction (k ~ N(0,0.8)).
// ---------------------------------------------------------------------------
__global__ __launch_bounds__(256)
void kv_context(const unsigned short* __restrict__ qkv,
                float* __restrict__ ctx_part, float* __restrict__ z_part)
{
    const int bh = blockIdx.x;
    const int sp = blockIdx.y;
    const int b = bh >> 3, h = bh & 7;
    const unsigned short* kb = qkv + ((size_t)b * CQKV + 256 + h * 32) * NN;
    const unsigned short* vb = qkv + ((size_t)b * CQKV + 512 + h * 32) * NN;
    const int c0 = sp * (NN / KSPLIT);

    __shared__ float ek[64][36];
    __shared__ float vv[64][36];

    const int t = threadIdx.x;
    const int lane = t & 63;
    const int w = t >> 6;

    float zloc[8];
#pragma unroll
    for (int p = 0; p < 8; ++p) zloc[p] = 0.f;

    const int d0 = (lane >> 3) * 4;
    const int e0 = (lane & 7) * 4;
    float acc[4][4];
#pragma unroll
    for (int i = 0; i < 4; ++i)
#pragma unroll
        for (int j = 0; j < 4; ++j) acc[i][j] = 0.f;

    for (int cc = 0; cc < NN / KSPLIT; cc += 64) {
#pragma unroll
        for (int p = 0; p < 8; ++p) {
            const int d = w + 4 * p;
            const float kvv = bf2f(kb[(size_t)d * NN + c0 + cc + lane]);
            const float e = __expf(kvv);
            zloc[p] += e;
            ek[lane][d] = e;
            vv[lane][d] = bf2f(vb[(size_t)d * NN + c0 + cc + lane]);
        }
        __syncthreads();
#pragma unroll
        for (int ci = 0; ci < 16; ++ci) {
            const int c = w + 4 * ci;
            float ea[4], va[4];
            *reinterpret_cast<float4*>(ea) = *reinterpret_cast<const float4*>(&ek[c][d0]);
            *reinterpret_cast<float4*>(va) = *reinterpret_cast<const float4*>(&vv[c][e0]);
#pragma unroll
            for (int i = 0; i < 4; ++i)
#pragma unroll
                for (int j = 0; j < 4; ++j)
                    acc[i][j] = fmaf(ea[i], va[j], acc[i][j]);
        }
        __syncthreads();
    }

    float* dst = ctx_part + (((size_t)bh * KSPLIT + sp) * 4 + w) * 1024 + lane * 16;
#pragma unroll
    for (int i = 0; i < 4; ++i) {
        float4 v;
        v.x = acc[i][0]; v.y = acc[i][1]; v.z = acc[i][2]; v.w = acc[i][3];
        *reinterpret_cast<float4*>(&dst[i * 4]) = v;
    }
#pragma unroll
    for (int p = 0; p < 8; ++p) {
        float z = zloc[p];
#pragma unroll
        for (int off = 32; off >= 1; off >>= 1) z += __shfl_xor(z, off);
        if (lane == 0) z_part[((size_t)bh * KSPLIT + sp) * 32 + (w + 4 * p)] = z;
    }
}

// ---------------------------------------------------------------------------
// K4: reduce context partials, normalize by Z, fold in w_out -> Mmat bf16
// ---------------------------------------------------------------------------
__global__ __launch_bounds__(256)
void make_m(const float* __restrict__ ctx_part, const float* __restrict__ z_part,
            const float* __restrict__ w_out, unsigned short* __restrict__ Mmat)
{
    const int h = blockIdx.x;
    const int b = blockIdx.y;
    const int bh = b * 8 + h;
    const int t = threadIdx.x;

    __shared__ float ctx[32][33];
    __shared__ float zinv[32];

    for (int lin = t; lin < 1024; lin += 256) {
        const int g = lin >> 4, i = (lin >> 2) & 3, j = lin & 3;
        const int d = ((g >> 3) << 2) + i;
        const int e = ((g & 7) << 2) + j;
        float s = 0.f;
#pragma unroll
        for (int p = 0; p < 16; ++p)
            s += ctx_part[((size_t)bh * 16 + p) * 1024 + lin];
        ctx[d][e] = s;
    }
    if (t < 32) {
        float z = 0.f;
#pragma unroll
        for (int sp = 0; sp < KSPLIT; ++sp)
            z += z_part[((size_t)bh * KSPLIT + sp) * 32 + t];
        zinv[t] = 1.f / z;
    }
    __syncthreads();

    const int o = t;
    float wrow[32];
#pragma unroll
    for (int e = 0; e < 32; ++e)
        wrow[e] = w_out[(size_t)o * 256 + h * 32 + e];
#pragma unroll 4
    for (int d = 0; d < 32; ++d) {
        float s = 0.f;
#pragma unroll
        for (int e = 0; e < 32; ++e)
            s = fmaf(wrow[e], ctx[d][e], s);
        Mmat[((size_t)b * 256 + o) * 256 + h * 32 + d] = f2bf(s * zinv[d]);
    }
}

// ---------------------------------------------------------------------------
extern "C" void kernel_launch(void* const* d_in, const int* in_sizes, int n_in,
                              void* d_out, int out_size, void* d_ws, size_t ws_size,
                              hipStream_t stream)
{
    const float* x     = (const float*)d_in[0];
    const float* w_qkv = (const float*)d_in[1];
    const float* w_out = (const float*)d_in[2];
    const float* b_out = (const float*)d_in[3];
    float* out = (float*)d_out;

    char* ws = (char*)d_ws;
    size_t off = 0;
    unsigned short* qkv = (unsigned short*)(ws + off);  off += (size_t)NBATCH * CQKV * NN * 2;   // 96 MiB
    unsigned short* xT  = (unsigned short*)(ws + off);  off += (size_t)NBATCH * NN * CIN * 2;    // 32 MiB
    unsigned short* qT  = (unsigned short*)(ws + off);  off += (size_t)NBATCH * NN * CIN * 2;    // 32 MiB
    float* ctx_part     = (float*)(ws + off);           off += (size_t)128 * 16 * 1024 * 4;      // 8 MiB
    float* z_part       = (float*)(ws + off);           off += (size_t)128 * KSPLIT * 32 * 4;
    unsigned short* Mmat= (unsigned short*)(ws + off);  off += (size_t)NBATCH * 256 * 256 * 2;   // 2 MiB
    unsigned short* wb  = (unsigned short*)(ws + off);  off += (size_t)CQKV * CIN * 2;

    // K0: transpose+cast x, cast w_qkv
    xpose<<<dim3(NN / 64, CIN / 64, NBATCH), 256, 0, stream>>>(x, xT);
    wcvt<<<dim3(CQKV * CIN / 1024), 256, 0, stream>>>(w_qkv, wb);

    // K1: qkv = w_qkv @ x  (q rows -> fused softmax+transpose into qT)
    gemm_qkv<<<dim3(32, 6, NBATCH), 256, 0, stream>>>(wb, xT, qkv, qT);

    // K2: context partials
    kv_context<<<dim3(128, KSPLIT), 256, 0, stream>>>(qkv, ctx_part, z_part);

    // K4: Mmat = fold(w_out, normalized context)
    make_m<<<dim3(8, NBATCH), 256, 0, stream>>>(ctx_part, z_part, w_out, Mmat);

    // K5: out = Mmat @ q + b_out
    gemm_out<<<dim3(32, 2, NBATCH), 256, 0, stream>>>(Mmat, qT, out, b_out);
}